// Round 1
// baseline (51.647 us; speedup 1.0000x reference)
//
#include <hip/hip_runtime.h>
#include <math.h>

#define HW 224
#define NCOL 56   // distinct DCT columns needed: {32*b + c : b in 0..6, c in 0..7}

// Orthonormal DCT-II matrix element M[r][k], exact integer range reduction:
// cos(pi*(2k+1)*r / (2*HW)) has period 4*HW in m=(2k+1)*r.
__device__ __forceinline__ float dctM(int r, int k) {
    int m = ((2 * k + 1) * r) % (4 * HW);               // m in [0, 896)
    float ang = (float)m * (3.14159265358979323846f / (2.0f * HW));
    float v = cosf(ang);
    // sqrt(2/224) = 0.09449111825230679; row 0 additionally * 1/sqrt(2)
    v *= (r == 0) ? 0.06681531047810609f : 0.09449111825230679f;
    return v;
}

// Kernel 1: per frame -> 128 features.
// feats come from dct rows {0,1,32,33} x cols {32b+c}, ordering:
//   f = bj*16 + r*8 + c            (rows 0/1,  bj=0..6)
//   f = 112 + r*8 + c              (rows 32/33, bj=0)
__global__ __launch_bounds__(512) void k1_feats(const float* __restrict__ img,
                                                float* __restrict__ feats) {
    __shared__ float msel[4 * HW];        // selected DCT rows (0,1,32,33)
    __shared__ float mcol[HW * NCOL];     // [w][jj] DCT column entries
    __shared__ float tpart[2 * 4 * HW];   // per-half partial row projections
    __shared__ float tmp[4 * HW];         // combined  M_sel @ gray

    const int tid = threadIdx.x;
    const int frame = blockIdx.x;

    // Phase A: build DCT tables in LDS
    for (int idx = tid; idx < 4 * HW; idx += 512) {
        int i = idx / HW, h = idx % HW;
        int r = (i < 2) ? i : (30 + i);   // 0,1,32,33
        msel[idx] = dctM(r, h);
    }
    for (int idx = tid; idx < HW * NCOL; idx += 512) {
        int w = idx / NCOL, jj = idx % NCOL;
        int j = ((jj >> 3) << 5) + (jj & 7);   // 32*b + c
        mcol[idx] = dctM(j, w);
    }
    __syncthreads();

    // Phase B: stream image, fuse gray conversion + row projection.
    // thread = (half, w): half covers 112 rows; w = column.
    const int w = tid & 255;
    const int half = tid >> 8;
    if (w < HW) {
        const float* p = img + (size_t)frame * (3 * HW * HW) + half * (112 * HW) + w;
        float a0 = 0.f, a1 = 0.f, a2 = 0.f, a3 = 0.f;
        const int hbase = half * 112;
        #pragma unroll 4
        for (int h = 0; h < 112; ++h) {
            float r = p[h * HW];
            float g = p[HW * HW + h * HW];
            float b = p[2 * HW * HW + h * HW];
            float ru = floorf(fminf(fmaxf(r * 255.f, 0.f), 255.f));
            float gu = floorf(fminf(fmaxf(g * 255.f, 0.f), 255.f));
            float bu = floorf(fminf(fmaxf(b * 255.f, 0.f), 255.f));
            float gray = rintf(0.299f * ru + 0.587f * gu + 0.114f * bu);
            int hh = hbase + h;
            a0 += msel[0 * HW + hh] * gray;
            a1 += msel[1 * HW + hh] * gray;
            a2 += msel[2 * HW + hh] * gray;
            a3 += msel[3 * HW + hh] * gray;
        }
        tpart[(half * 4 + 0) * HW + w] = a0;
        tpart[(half * 4 + 1) * HW + w] = a1;
        tpart[(half * 4 + 2) * HW + w] = a2;
        tpart[(half * 4 + 3) * HW + w] = a3;
    }
    __syncthreads();
    for (int idx = tid; idx < 4 * HW; idx += 512)
        tmp[idx] = tpart[idx] + tpart[4 * HW + idx];
    __syncthreads();

    // Phase C: second projection (4 x 56) and scatter to the 128 kept feats.
    if (tid < 4 * NCOL) {
        int i = tid / NCOL, jj = tid % NCOL;
        float s = 0.f;
        #pragma unroll 8
        for (int w2 = 0; w2 < HW; ++w2)
            s += tmp[i * HW + w2] * mcol[w2 * NCOL + jj];
        int f = -1;
        if (i < 2) {
            f = (jj >> 3) * 16 + i * 8 + (jj & 7);
        } else if (jj < 8) {
            f = 112 + (i - 2) * 8 + jj;
        }
        if (f >= 0) feats[frame * 128 + f] = s;
    }
}

// Kernel 2: h = relu(feats @ w1^T + b1). Tile: 16 frames x 16 outputs per block.
__global__ __launch_bounds__(256) void k2_fc1(const float* __restrict__ feats,
                                              const float* __restrict__ w1,
                                              const float* __restrict__ b1,
                                              float* __restrict__ hbuf) {
    __shared__ float sA[16 * 129];
    __shared__ float sW[16 * 129];
    const int tid = threadIdx.x;
    const int fg = blockIdx.x, og = blockIdx.y;
    for (int idx = tid; idx < 16 * 128; idx += 256) {
        int r = idx >> 7, c = idx & 127;
        sA[r * 129 + c] = feats[(fg * 16 + r) * 128 + c];
        sW[r * 129 + c] = w1[(og * 16 + r) * 128 + c];
    }
    __syncthreads();
    const int fr = tid >> 4, o = tid & 15;
    float s = 0.f;
    #pragma unroll 8
    for (int f = 0; f < 128; ++f)
        s += sA[fr * 129 + f] * sW[o * 129 + f];
    s += b1[og * 16 + o];
    hbuf[(fg * 16 + fr) * 256 + og * 16 + o] = fmaxf(s, 0.f);
}

// Kernel 3: out = h @ w2^T + b2. Tile: 16 frames x 16 outputs per block.
__global__ __launch_bounds__(256) void k3_fc2(const float* __restrict__ hbuf,
                                              const float* __restrict__ w2,
                                              const float* __restrict__ b2,
                                              float* __restrict__ out) {
    __shared__ float sH[16 * 257];
    __shared__ float sW[16 * 257];
    const int tid = threadIdx.x;
    const int fg = blockIdx.x, eg = blockIdx.y;
    for (int idx = tid; idx < 16 * 256; idx += 256) {
        int r = idx >> 8, c = idx & 255;
        sH[r * 257 + c] = hbuf[(fg * 16 + r) * 256 + c];
        sW[r * 257 + c] = w2[(eg * 16 + r) * 256 + c];
    }
    __syncthreads();
    const int fr = tid >> 4, e = tid & 15;
    float s = 0.f;
    #pragma unroll 8
    for (int k = 0; k < 256; ++k)
        s += sH[fr * 257 + k] * sW[e * 257 + k];
    s += b2[eg * 16 + e];
    out[(fg * 16 + fr) * 768 + eg * 16 + e] = s;
}

extern "C" void kernel_launch(void* const* d_in, const int* in_sizes, int n_in,
                              void* d_out, int out_size, void* d_ws, size_t ws_size,
                              hipStream_t stream) {
    const float* img = (const float*)d_in[0];   // [8,32,3,224,224]
    const float* w1  = (const float*)d_in[1];   // [256,128]
    const float* b1  = (const float*)d_in[2];   // [256]
    const float* w2  = (const float*)d_in[3];   // [768,256]
    const float* b2  = (const float*)d_in[4];   // [768]
    float* out = (float*)d_out;                 // [256,768]

    float* feats = (float*)d_ws;                // [256][128]
    float* hbuf  = feats + 256 * 128;           // [256][256]

    k1_feats<<<256, 512, 0, stream>>>(img, feats);
    k2_fc1<<<dim3(16, 16), 256, 0, stream>>>(feats, w1, b1, hbuf);
    k3_fc2<<<dim3(16, 48), 256, 0, stream>>>(hbuf, w2, b2, out);
}